// Round 2
// baseline (123.241 us; speedup 1.0000x reference)
//
#include <hip/hip_runtime.h>
#include <cstddef>

#define BB 16
#define PP 4
#define HH 32
#define WW 32
#define DD 32
#define CC 8

typedef float fx4 __attribute__((ext_vector_type(4)));

// R6 (resubmit after infra failure "container failed twice" in R1 — no
// kernel-side error was reported; source re-audited for OOB: all accesses
// in-bounds): one thread = ONE full voxel (all 8 channels).
// Rationale: the previous half-channel split made the half=0/half=1 thread
// pair duplicate the entire coordinate/floor/clamp/weight computation for
// the same voxel (~2x the address VALU of the whole kernel). Full-channel
// threads halve total VALU, keep the same 16-loads-in-flight batch per
// thread (8 corners x 2 dwordx4 sharing one 32-bit voffset, hi half via
// imm offset:16), and make the store address simply g*8 (output-linear,
// 2KB contiguous per wave).
// __launch_bounds__(256,4): cap VGPR at 128 so the scheduler cannot
// balloon liveness past 4 waves/SIMD (R5 lesson: control the allocator).
__global__ __launch_bounds__(256, 4) void resample_kernel(
    const float* __restrict__ fmap,
    const float* __restrict__ theta,
    float* __restrict__ out)
{
    const int g  = blockIdx.x * 256 + threadIdx.x;   // global voxel id
    const int bp = g >> 15;                          // (b,p): 32768 voxels each
    const int r  = g & 32767;
    const int h  = r >> 10;
    const int w  = (r >> 5) & 31;
    const int d  = r & 31;

    const float* th = theta + bp * 12;               // uniform -> s_load
    const float t0 = th[0], t1 = th[1], t2  = th[2],  t3  = th[3];
    const float t4 = th[4], t5 = th[5], t6  = th[6],  t7  = th[7];
    const float t8 = th[8], t9 = th[9], t10 = th[10], t11 = th[11];

    const float fw = (float)w, fh = (float)h, fd = (float)d;
    // meshgrid 'xy': grid point is (x=w, y=h, z=d); +2 pad offset
    const float x = fmaf(t0, fw, fmaf(t1, fh, fmaf(t2,  fd, t3 ))) + 2.0f;
    const float y = fmaf(t4, fw, fmaf(t5, fh, fmaf(t6,  fd, t7 ))) + 2.0f;
    const float z = fmaf(t8, fw, fmaf(t9, fh, fmaf(t10, fd, t11))) + 2.0f;

    // faithful: floor -> clip to [0, H+2] in padded coords (all axes H+2)
    const int x0 = min(max((int)floorf(x), 0), HH + 2);
    const int y0 = min(max((int)floorf(y), 0), HH + 2);
    const int z0 = min(max((int)floorf(z), 0), HH + 2);
    const float xd = x - (float)x0, yd = y - (float)y0, zd = z - (float)z0;

    const int ix[2] = { x0 - 2, x0 - 1 };            // x indexes the H axis (ref quirk)
    const int iy[2] = { y0 - 2, y0 - 1 };
    const int iz[2] = { z0 - 2, z0 - 1 };
    const float wxv[2] = { (1.0f - xd) * (((unsigned)ix[0] < (unsigned)HH) ? 1.0f : 0.0f),
                           xd          * (((unsigned)ix[1] < (unsigned)HH) ? 1.0f : 0.0f) };
    const float wyv[2] = { (1.0f - yd) * (((unsigned)iy[0] < (unsigned)WW) ? 1.0f : 0.0f),
                           yd          * (((unsigned)iy[1] < (unsigned)WW) ? 1.0f : 0.0f) };
    const float wzv[2] = { (1.0f - zd) * (((unsigned)iz[0] < (unsigned)DD) ? 1.0f : 0.0f),
                           zd          * (((unsigned)iz[1] < (unsigned)DD) ? 1.0f : 0.0f) };
    const unsigned ox[2] = { (unsigned)(min(max(ix[0], 0), HH - 1) * (WW * DD * CC)),
                             (unsigned)(min(max(ix[1], 0), HH - 1) * (WW * DD * CC)) };
    const unsigned oy[2] = { (unsigned)(min(max(iy[0], 0), WW - 1) * (DD * CC)),
                             (unsigned)(min(max(iy[1], 0), WW - 1) * (DD * CC)) };
    const unsigned oz[2] = { (unsigned)(min(max(iz[0], 0), DD - 1) * CC),
                             (unsigned)(min(max(iz[1], 0), DD - 1) * CC) };

    const float* __restrict__ base = fmap + (size_t)bp * (HH * WW * DD * CC);

    unsigned voff[8];
    float    wgt[8];
    #pragma unroll
    for (int i = 0; i < 8; ++i) {
        const int bx = (i >> 2) & 1, by = (i >> 1) & 1, bz = i & 1;
        voff[i] = ox[bx] + oy[by] + oz[bz];
        wgt[i]  = wxv[bx] * wyv[by] * wzv[bz];
    }

    // ---- load phase: 16 independent global_load_dwordx4, all in flight ----
    fx4 clo[8], chi[8];
    #pragma unroll
    for (int i = 0; i < 8; ++i) {
        clo[i] = *(const fx4*)(base + voff[i]);
        chi[i] = *(const fx4*)(base + voff[i] + 4);  // same voffset, offset:16
    }
    // Hard scheduling fence: loads stay batched; no FMA/waitcnt hoists above.
    __builtin_amdgcn_sched_barrier(0);

    // ---- consume phase ----
    fx4 alo = (fx4){0.f, 0.f, 0.f, 0.f};
    fx4 ahi = (fx4){0.f, 0.f, 0.f, 0.f};
    #pragma unroll
    for (int i = 0; i < 8; ++i) {
        const float gw = wgt[i];
        alo.x = fmaf(gw, clo[i].x, alo.x);
        alo.y = fmaf(gw, clo[i].y, alo.y);
        alo.z = fmaf(gw, clo[i].z, alo.z);
        alo.w = fmaf(gw, clo[i].w, alo.w);
        ahi.x = fmaf(gw, chi[i].x, ahi.x);
        ahi.y = fmaf(gw, chi[i].y, ahi.y);
        ahi.z = fmaf(gw, chi[i].z, ahi.z);
        ahi.w = fmaf(gw, chi[i].w, ahi.w);
    }

    // g enumerates voxels exactly in output order -> coalesced 2KB/wave
    float* o = out + (size_t)g * CC;
    __builtin_nontemporal_store(alo, (fx4*)o);
    __builtin_nontemporal_store(ahi, (fx4*)(o + 4));
}

extern "C" void kernel_launch(void* const* d_in, const int* in_sizes, int n_in,
                              void* d_out, int out_size, void* d_ws, size_t ws_size,
                              hipStream_t stream) {
    const float* fmap  = (const float*)d_in[0];
    const float* theta = (const float*)d_in[1];
    float* out = (float*)d_out;

    const int total_blocks = (BB * PP * HH * WW * DD) / 256;  // 8192, 1 voxel/thread
    resample_kernel<<<dim3(total_blocks), dim3(256), 0, stream>>>(fmap, theta, out);
}